// Round 2
// baseline (59912.842 us; speedup 1.0000x reference)
//
#include <hip/hip_runtime.h>
#include <hip/hip_fp16.h>

#define B_   32
#define T_   1024
#define H_   1024
#define NL_  4
#define NBLK 256
#define NTHR 256

typedef _Float16 half8 __attribute__((ext_vector_type(8)));
typedef float    f32x4 __attribute__((ext_vector_type(4)));

// ---- persistent-kernel grid barrier (device-scope, monotonic counter) ----
// Counter is zeroed by a captured hipMemsetAsync before every launch, so
// replays are self-consistent. Release fence before the add publishes this
// block's h stores; acquire fence after the poll makes peers' stores visible
// (per-XCD L2s are not cross-coherent without device-scope ordering).
__device__ __forceinline__ void gbar(unsigned long long* cnt, unsigned long long target) {
  __threadfence();
  __syncthreads();
  if (threadIdx.x == 0) {
    __hip_atomic_fetch_add(cnt, 1ull, __ATOMIC_RELEASE, __HIP_MEMORY_SCOPE_AGENT);
    while (__hip_atomic_load(cnt, __ATOMIC_RELAXED, __HIP_MEMORY_SCOPE_AGENT) < target)
      __builtin_amdgcn_s_sleep(1);
  }
  __syncthreads();
  __threadfence();
}

__device__ __forceinline__ half8 cvt8(const float* p) {
  float4 u = *(const float4*)p;
  float4 v = *(const float4*)(p + 4);
  half8 r;
  r[0]=(_Float16)u.x; r[1]=(_Float16)u.y; r[2]=(_Float16)u.z; r[3]=(_Float16)u.w;
  r[4]=(_Float16)v.x; r[5]=(_Float16)v.y; r[6]=(_Float16)v.z; r[7]=(_Float16)v.w;
  return r;
}

// Grid: 256 blocks = 4 layers x 64 col-blocks (16 hidden cols each), 256 thr.
// Layer-pipelined wavefront: layer l computes timestep t at global step
// s = t + l, so the critical path is T+NL-1 = 1027 grid barriers, not T*NL.
// Per step/block: out[32x16] = in[32x1024]@Wi_slice + h_own[32x1024]@Wh_slice,
// K split 4 ways across the 4 waves, reduced via LDS, +bias, tanh, fp16 store.
// Weights stay pinned in VGPRs for the whole kernel (zero steady-state weight
// traffic). MFMA A/B fragments use the same (lane-group,j)->k formula, so the
// result is invariant to the hardware's exact k mapping (k-permutation trick).
extern "C" __global__ void __launch_bounds__(NTHR)
rnn_persist(const float* __restrict__ x,  const float* __restrict__ Wi,
            const float* __restrict__ Wh, const float* __restrict__ bias,
            const float* __restrict__ fcW,const float* __restrict__ fcb,
            float* __restrict__ out, unsigned char* __restrict__ ws)
{
  __shared__ float red[8*256];   // [wave*2+mtile][col*16 + row]
  __shared__ float blds[16];

  unsigned long long* cnt = (unsigned long long*)ws;
  _Float16* hbuf  = (_Float16*)(ws + 4096);                    // [NL][2][B_][H_] fp16 ring
  float*    hlast = (float*)(ws + 4096 + NL_*2*B_*H_*2);       // [B_][H_] fp32

  const int tid = threadIdx.x;
  const int bid = blockIdx.x;
  const int l   = bid >> 6;       // layer
  const int cb  = bid & 63;       // 16-col block
  const int wv  = tid >> 6;       // wave id
  const int ln  = tid & 63;
  const int lq  = ln & 15;        // A batch-row / B col / D col
  const int lg  = ln >> 4;        // k-group

  // ---- one-time: pin this block's weight slices in VGPRs (fragment order) ----
  half8 bfr[16];                  // [0..7] Wi k-tiles, [8..15] Wh k-tiles
  {
    const float* Wl  = Wi + (size_t)l*H_*H_;
    const float* Whl = Wh + (size_t)l*H_*H_;
    #pragma unroll
    for (int q = 0; q < 8; ++q) {
      const int kt = wv*8 + q;
      const float* s0 = Wl  + (size_t)(kt*32 + lg*8)*H_ + cb*16 + lq;
      const float* s1 = Whl + (size_t)(kt*32 + lg*8)*H_ + cb*16 + lq;
      half8 f0, f1;
      #pragma unroll
      for (int j = 0; j < 8; ++j) {
        f0[j] = (_Float16)s0[(size_t)j*H_];
        f1[j] = (_Float16)s1[(size_t)j*H_];
      }
      bfr[q]   = f0;
      bfr[8+q] = f1;
    }
  }
  if (tid < 16) blds[tid] = bias[l*H_ + cb*16 + tid];

  unsigned long long ep = 0;

  // ---- layer-pipelined recurrence: layer l handles t = s - l ----
  for (int s = 0; s < T_ + NL_ - 1; ++s) {
    const int t = s - l;
    if ((unsigned)t < (unsigned)T_) {
      f32x4 acc0 = {0.f,0.f,0.f,0.f};
      f32x4 acc1 = {0.f,0.f,0.f,0.f};

      if (l == 0) {  // input = x[:, t, :] fp32, convert on the fly
        const float* px = x + (size_t)lq*(T_*H_) + (size_t)t*H_ + lg*8;
        #pragma unroll
        for (int q = 0; q < 8; ++q) {
          const int kt = wv*8 + q;
          half8 a0 = cvt8(px + kt*32);
          half8 a1 = cvt8(px + (size_t)16*(T_*H_) + kt*32);
          acc0 = __builtin_amdgcn_mfma_f32_16x16x32_f16(a0, bfr[q], acc0, 0,0,0);
          acc1 = __builtin_amdgcn_mfma_f32_16x16x32_f16(a1, bfr[q], acc1, 0,0,0);
        }
      } else {       // input = previous layer's h at time t (fp16 ring)
        const _Float16* pi = hbuf + ((l-1)*2 + (t&1))*(B_*H_) + lq*H_ + lg*8;
        #pragma unroll
        for (int q = 0; q < 8; ++q) {
          const int kt = wv*8 + q;
          half8 a0 = *(const half8*)(pi + kt*32);
          half8 a1 = *(const half8*)(pi + 16*H_ + kt*32);
          acc0 = __builtin_amdgcn_mfma_f32_16x16x32_f16(a0, bfr[q], acc0, 0,0,0);
          acc1 = __builtin_amdgcn_mfma_f32_16x16x32_f16(a1, bfr[q], acc1, 0,0,0);
        }
      }
      if (t > 0) {   // recurrent term h_{t-1} @ Wh
        const _Float16* ph = hbuf + (l*2 + ((t-1)&1))*(B_*H_) + lq*H_ + lg*8;
        #pragma unroll
        for (int q = 0; q < 8; ++q) {
          const int kt = wv*8 + q;
          half8 a0 = *(const half8*)(ph + kt*32);
          half8 a1 = *(const half8*)(ph + 16*H_ + kt*32);
          acc0 = __builtin_amdgcn_mfma_f32_16x16x32_f16(a0, bfr[8+q], acc0, 0,0,0);
          acc1 = __builtin_amdgcn_mfma_f32_16x16x32_f16(a1, bfr[8+q], acc1, 0,0,0);
        }
      }

      // cross-wave K reduction via LDS. C/D layout (m89-verified):
      // col = lane&15, row = (lane>>4)*4 + i.
      *(f32x4*)(red + (wv*2+0)*256 + lq*16 + lg*4) = acc0;
      *(f32x4*)(red + (wv*2+1)*256 + lq*16 + lg*4) = acc1;
      __syncthreads();

      const int m  = tid >> 7;          // batch tile (rows 0-15 / 16-31)
      const int c  = (tid & 127) >> 3;  // hidden col within block
      const int r0 = (tid & 7) * 2;     // batch-row pair within tile
      const float* p0 = red + m*256 + c*16 + r0;
      float s0 = p0[0] + p0[512] + p0[1024] + p0[1536];
      float s1 = p0[1] + p0[513] + p0[1025] + p0[1537];
      const float bb = blds[c];
      const float h0 = tanhf(s0 + bb);
      const float h1 = tanhf(s1 + bb);
      const int b0 = m*16 + r0;
      const int hc = cb*16 + c;
      _Float16* ho = hbuf + (l*2 + (t&1))*(B_*H_);
      ho[(size_t)b0*H_ + hc]     = (_Float16)h0;
      ho[(size_t)(b0+1)*H_ + hc] = (_Float16)h1;
      if (l == NL_-1 && t == T_-1) {    // keep final h in fp32 for the head
        hlast[b0*H_ + hc]     = h0;
        hlast[(b0+1)*H_ + hc] = h1;
      }
    }
    ++ep;
    gbar(cnt, ep*(unsigned long long)NBLK);
  }

  // ---- dense head: out = hlast @ fcW + fcb, 4 cols per block ----
  if (tid < 128) {
    const int c = bid*4 + (tid & 3);
    const int b = tid >> 2;
    const float* hv = hlast + (size_t)b*H_;
    const float* wp = fcW + c;
    float a0=0.f, a1=0.f, a2=0.f, a3=0.f;
    for (int k = 0; k < H_; k += 4) {
      a0 += hv[k+0] * wp[(size_t)(k+0)*H_];
      a1 += hv[k+1] * wp[(size_t)(k+1)*H_];
      a2 += hv[k+2] * wp[(size_t)(k+2)*H_];
      a3 += hv[k+3] * wp[(size_t)(k+3)*H_];
    }
    out[(size_t)b*H_ + c] = fcb[c] + a0 + a1 + a2 + a3;
  }
}

extern "C" void kernel_launch(void* const* d_in, const int* in_sizes, int n_in,
                              void* d_out, int out_size, void* d_ws, size_t ws_size,
                              hipStream_t stream) {
  const float* x   = (const float*)d_in[0];
  const float* Wi  = (const float*)d_in[1];
  const float* Wh  = (const float*)d_in[2];
  const float* b   = (const float*)d_in[3];
  const float* fcW = (const float*)d_in[4];
  const float* fcb = (const float*)d_in[5];
  float* out = (float*)d_out;
  unsigned char* ws = (unsigned char*)d_ws;

  // barrier counter lives in ws[0..4096) and is poisoned each call -> zero it
  hipMemsetAsync(d_ws, 0, 4096, stream);

  void* args[] = { (void*)&x, (void*)&Wi, (void*)&Wh, (void*)&b,
                   (void*)&fcW, (void*)&fcb, (void*)&out, (void*)&ws };
  hipLaunchCooperativeKernel((const void*)rnn_persist, dim3(NBLK), dim3(NTHR),
                             args, 0, stream);
}

// Round 4
// 24422.748 us; speedup vs baseline: 2.4532x; 2.4532x over previous
//
#include <hip/hip_runtime.h>
#include <hip/hip_fp16.h>

#define B_   32
#define T_   1024
#define H_   1024
#define NL_  4
#define NBLK 256
#define NTHR 256
#define FLAG_STRIDE 32   // uints -> 128 B per flag (one cache line each)

typedef _Float16 half8 __attribute__((ext_vector_type(8)));
typedef float    f32x4 __attribute__((ext_vector_type(4)));

// ---- symmetric flag barrier: zero contended RMWs ----------------------------
// R2 post-mortem: a single atomic counter + 256 spinners cost 55.6 us/step
// (256 serialized same-line RMWs across 8 non-coherent XCD L2s). Here each
// block release-stores an epoch to its OWN cache line (parallel), and thread t
// of every block polls flag[t] (256 distinct lines, read-shared, parallel).
// Happens-before: blockA stores h -> syncthreads (vmcnt drain) -> release
// flag[A] -> observed by thread A of block B -> acquire fence -> syncthreads
// -> all of block B reads h. Flags are zeroed by the captured memset each
// launch; epochs count up from 1, so graph replays are self-consistent.
__device__ __forceinline__ void gbar(unsigned* arrive, unsigned ep) {
  __syncthreads();
  if (threadIdx.x == 0)
    __hip_atomic_store(arrive + (size_t)blockIdx.x * FLAG_STRIDE, ep,
                       __ATOMIC_RELEASE, __HIP_MEMORY_SCOPE_AGENT);
  unsigned* f = arrive + (size_t)threadIdx.x * FLAG_STRIDE;
  while (__hip_atomic_load(f, __ATOMIC_RELAXED, __HIP_MEMORY_SCOPE_AGENT) < ep)
    __builtin_amdgcn_s_sleep(1);
  __builtin_amdgcn_fence(__ATOMIC_ACQUIRE, "agent");
  __syncthreads();
}

__device__ __forceinline__ half8 cvt8(const float* p) {
  float4 u = *(const float4*)p;
  float4 v = *(const float4*)(p + 4);
  half8 r;
  r[0]=(_Float16)u.x; r[1]=(_Float16)u.y; r[2]=(_Float16)u.z; r[3]=(_Float16)u.w;
  r[4]=(_Float16)v.x; r[5]=(_Float16)v.y; r[6]=(_Float16)v.z; r[7]=(_Float16)v.w;
  return r;
}

// Grid: 256 blocks = 4 layers x 64 col-blocks (16 hidden cols each), 256 thr.
// Layer-pipelined wavefront: layer l computes timestep t at step s = t + l;
// critical path = T+NL-1 = 1027 barriers. Weights pinned in VGPRs for the
// whole kernel. MFMA A/B fragments use the same (lane-group,j)->k formula, so
// the result is invariant to the exact hardware k mapping.
extern "C" __global__ void __launch_bounds__(NTHR)
rnn_persist(const float* __restrict__ x,  const float* __restrict__ Wi,
            const float* __restrict__ Wh, const float* __restrict__ bias,
            const float* __restrict__ fcW,const float* __restrict__ fcb,
            float* __restrict__ out, unsigned char* __restrict__ ws)
{
  __shared__ float red[8*256];   // [wave*2+mtile][col*16 + row]
  __shared__ float blds[16];

  unsigned* arrive = (unsigned*)ws;                            // 256 x 128 B
  _Float16* hbuf   = (_Float16*)(ws + 65536);                  // [NL][2][B_][H_] fp16 ring
  float*    hlast  = (float*)(ws + 65536 + (size_t)NL_*2*B_*H_*2); // [B_][H_] fp32

  const int tid = threadIdx.x;
  const int bid = blockIdx.x;
  const int l   = bid >> 6;       // layer
  const int cb  = bid & 63;       // 16-col block
  const int wv  = tid >> 6;       // wave id
  const int ln  = tid & 63;
  const int lq  = ln & 15;        // A batch-row / B col / D col
  const int lg  = ln >> 4;        // k-group

  // ---- one-time: pin this block's weight slices in VGPRs (fragment order) ----
  half8 bfr[16];                  // [0..7] Wi k-tiles, [8..15] Wh k-tiles
  {
    const float* Wl  = Wi + (size_t)l*H_*H_;
    const float* Whl = Wh + (size_t)l*H_*H_;
    #pragma unroll
    for (int q = 0; q < 8; ++q) {
      const int kt = wv*8 + q;
      const float* s0 = Wl  + (size_t)(kt*32 + lg*8)*H_ + cb*16 + lq;
      const float* s1 = Whl + (size_t)(kt*32 + lg*8)*H_ + cb*16 + lq;
      half8 f0, f1;
      #pragma unroll
      for (int j = 0; j < 8; ++j) {
        f0[j] = (_Float16)s0[(size_t)j*H_];
        f1[j] = (_Float16)s1[(size_t)j*H_];
      }
      bfr[q]   = f0;
      bfr[8+q] = f1;
    }
  }
  if (tid < 16) blds[tid] = bias[l*H_ + cb*16 + tid];

  unsigned ep = 0;

  // ---- layer-pipelined recurrence: layer l handles t = s - l ----
  for (int s = 0; s < T_ + NL_ - 1; ++s) {
    const int t = s - l;
    if ((unsigned)t < (unsigned)T_) {
      f32x4 acc0 = {0.f,0.f,0.f,0.f};
      f32x4 acc1 = {0.f,0.f,0.f,0.f};

      if (l == 0) {  // input = x[:, t, :] fp32, convert on the fly
        const float* px = x + (size_t)lq*(T_*H_) + (size_t)t*H_ + lg*8;
        #pragma unroll
        for (int q = 0; q < 8; ++q) {
          const int kt = wv*8 + q;
          half8 a0 = cvt8(px + kt*32);
          half8 a1 = cvt8(px + (size_t)16*(T_*H_) + kt*32);
          acc0 = __builtin_amdgcn_mfma_f32_16x16x32_f16(a0, bfr[q], acc0, 0,0,0);
          acc1 = __builtin_amdgcn_mfma_f32_16x16x32_f16(a1, bfr[q], acc1, 0,0,0);
        }
      } else {       // input = previous layer's h at time t (fp16 ring)
        const _Float16* pi = hbuf + ((l-1)*2 + (t&1))*(B_*H_) + lq*H_ + lg*8;
        #pragma unroll
        for (int q = 0; q < 8; ++q) {
          const int kt = wv*8 + q;
          half8 a0 = *(const half8*)(pi + kt*32);
          half8 a1 = *(const half8*)(pi + 16*H_ + kt*32);
          acc0 = __builtin_amdgcn_mfma_f32_16x16x32_f16(a0, bfr[q], acc0, 0,0,0);
          acc1 = __builtin_amdgcn_mfma_f32_16x16x32_f16(a1, bfr[q], acc1, 0,0,0);
        }
      }
      if (t > 0) {   // recurrent term h_{t-1} @ Wh
        const _Float16* ph = hbuf + (l*2 + ((t-1)&1))*(B_*H_) + lq*H_ + lg*8;
        #pragma unroll
        for (int q = 0; q < 8; ++q) {
          const int kt = wv*8 + q;
          half8 a0 = *(const half8*)(ph + kt*32);
          half8 a1 = *(const half8*)(ph + 16*H_ + kt*32);
          acc0 = __builtin_amdgcn_mfma_f32_16x16x32_f16(a0, bfr[8+q], acc0, 0,0,0);
          acc1 = __builtin_amdgcn_mfma_f32_16x16x32_f16(a1, bfr[8+q], acc1, 0,0,0);
        }
      }

      // cross-wave K reduction via LDS. C/D layout (m89-verified):
      // col = lane&15, row = (lane>>4)*4 + i.
      *(f32x4*)(red + (wv*2+0)*256 + lq*16 + lg*4) = acc0;
      *(f32x4*)(red + (wv*2+1)*256 + lq*16 + lg*4) = acc1;
      __syncthreads();

      // epilogue map: col fastest across threads -> coalesced fp16 stores
      const int m    = tid >> 7;          // batch tile (rows 0-15 / 16-31)
      const int col  = tid & 15;          // hidden col within block
      const int row8 = (tid >> 4) & 7;    // rows row8 and row8+8
      const float* p0 = red + m*256 + col*16 + row8;
      float s0 = p0[0] + p0[512] + p0[1024] + p0[1536];
      float s1 = p0[8] + p0[520] + p0[1032] + p0[1544];
      const float bb = blds[col];
      const float h0 = tanhf(s0 + bb);
      const float h1 = tanhf(s1 + bb);
      const int b0 = m*16 + row8;
      const int hc = cb*16 + col;
      _Float16* ho = hbuf + (l*2 + (t&1))*(B_*H_);
      ho[(size_t)b0*H_ + hc]     = (_Float16)h0;
      ho[(size_t)(b0+8)*H_ + hc] = (_Float16)h1;
      if (l == NL_-1 && t == T_-1) {      // keep final h in fp32 for the head
        hlast[b0*H_ + hc]     = h0;
        hlast[(b0+8)*H_ + hc] = h1;
      }
    }
    ++ep;
    gbar(arrive, ep);
  }

  // ---- dense head: out = hlast @ fcW + fcb, 4 cols per block ----
  if (tid < 128) {
    const int c = bid*4 + (tid & 3);
    const int b = tid >> 2;
    const float* hv = hlast + (size_t)b*H_;
    const float* wp = fcW + c;
    float a0=0.f, a1=0.f, a2=0.f, a3=0.f;
    for (int k = 0; k < H_; k += 4) {
      a0 += hv[k+0] * wp[(size_t)(k+0)*H_];
      a1 += hv[k+1] * wp[(size_t)(k+1)*H_];
      a2 += hv[k+2] * wp[(size_t)(k+2)*H_];
      a3 += hv[k+3] * wp[(size_t)(k+3)*H_];
    }
    out[(size_t)b*H_ + c] = fcb[c] + a0 + a1 + a2 + a3;
  }
}

extern "C" void kernel_launch(void* const* d_in, const int* in_sizes, int n_in,
                              void* d_out, int out_size, void* d_ws, size_t ws_size,
                              hipStream_t stream) {
  const float* x   = (const float*)d_in[0];
  const float* Wi  = (const float*)d_in[1];
  const float* Wh  = (const float*)d_in[2];
  const float* b   = (const float*)d_in[3];
  const float* fcW = (const float*)d_in[4];
  const float* fcb = (const float*)d_in[5];
  float* out = (float*)d_out;
  unsigned char* ws = (unsigned char*)d_ws;

  // flag region (256 x 128 B) is poisoned each call -> zero it
  hipMemsetAsync(d_ws, 0, 65536, stream);

  void* args[] = { (void*)&x, (void*)&Wi, (void*)&Wh, (void*)&b,
                   (void*)&fcW, (void*)&fcb, (void*)&out, (void*)&ws };
  hipLaunchCooperativeKernel((const void*)rnn_persist, dim3(NBLK), dim3(NTHR),
                             args, 0, stream);
}